// Round 1
// baseline (6050.076 us; speedup 1.0000x reference)
//
#include <hip/hip_runtime.h>
#include <hip/hip_bf16.h>

#define H_Q 16
#define H_KV 4
#define HD 80
#define QKV_ROW 1920   // (16 + 2*4) * 80
#define K_OFF 1280     // 16*80
#define V_OFF 1600     // 16*80 + 4*80
#define EMB 1280
#define MAXSEG 4096
#define CHUNK 64

// ---------------- fp32 GEMM: C[M,N] = A[M,K] * B[N,K]^T ----------------
// 64x64 tile, 256 threads, 4x4 per thread, BK=16.
__global__ __launch_bounds__(256) void gemm_rr(const float* __restrict__ A,
                                               const float* __restrict__ B,
                                               float* __restrict__ C,
                                               int M, int N, int K) {
  __shared__ float As[16][64];
  __shared__ float Bs[16][64];
  const int bm = blockIdx.y * 64;
  const int bn = blockIdx.x * 64;
  const int tid = threadIdx.x;
  const int tx = tid & 15;
  const int ty = tid >> 4;
  float acc[4][4] = {};
  for (int k0 = 0; k0 < K; k0 += 16) {
    // each thread loads 4 consecutive k of one row (float4), for A and B
    const int i  = tid * 4;
    const int m  = i >> 4;   // row within tile
    const int kk = i & 15;   // k within tile (0,4,8,12)
    float4 va = *reinterpret_cast<const float4*>(&A[(size_t)(bm + m) * K + k0 + kk]);
    As[kk + 0][m] = va.x; As[kk + 1][m] = va.y; As[kk + 2][m] = va.z; As[kk + 3][m] = va.w;
    float4 vb = *reinterpret_cast<const float4*>(&B[(size_t)(bn + m) * K + k0 + kk]);
    Bs[kk + 0][m] = vb.x; Bs[kk + 1][m] = vb.y; Bs[kk + 2][m] = vb.z; Bs[kk + 3][m] = vb.w;
    __syncthreads();
    #pragma unroll
    for (int k = 0; k < 16; ++k) {
      float a[4], b[4];
      #pragma unroll
      for (int u = 0; u < 4; ++u) a[u] = As[k][ty * 4 + u];
      #pragma unroll
      for (int u = 0; u < 4; ++u) b[u] = Bs[k][tx * 4 + u];
      #pragma unroll
      for (int x = 0; x < 4; ++x)
        #pragma unroll
        for (int y = 0; y < 4; ++y)
          acc[x][y] += a[x] * b[y];
    }
    __syncthreads();
  }
  #pragma unroll
  for (int x = 0; x < 4; ++x)
    #pragma unroll
    for (int y = 0; y < 4; ++y)
      C[(size_t)(bm + ty * 4 + x) * N + bn + tx * 4 + y] = acc[x][y];
}

// ---------------- per-head RMSNorm + RoPE (in place on q,k of qkv) ----------------
// grid = (T, 20): h 0..15 -> q heads, 16..19 -> k heads. block = 64 (one wave).
__global__ __launch_bounds__(64) void norm_rope_kernel(float* __restrict__ qkv,
                                                       const float* __restrict__ freqs,
                                                       const float* __restrict__ qw,
                                                       const float* __restrict__ kw) {
  const int t = blockIdx.x;
  const int h = blockIdx.y;
  const int lane = threadIdx.x;
  const bool is_q = (h < H_Q);
  float* x = qkv + (size_t)t * QKV_ROW + (is_q ? h * HD : K_OFF + (h - H_Q) * HD);
  const float* w = is_q ? qw : kw;
  float a = x[lane];
  float b = (lane < HD - 64) ? x[64 + lane] : 0.0f;
  float ss = a * a + b * b;
  #pragma unroll
  for (int off = 32; off; off >>= 1) ss += __shfl_down(ss, off);
  ss = __shfl(ss, 0);
  const float inv = rsqrtf(ss / (float)HD + 1e-6f);
  __shared__ float xs[HD];
  xs[lane] = a * inv * w[lane];
  if (lane < HD - 64) xs[64 + lane] = b * inv * w[64 + lane];
  __syncthreads();
  const float* f = freqs + (size_t)t * HD;
  {
    const int d = lane;
    const float fr = f[d];
    const float rot = (d < HD / 2) ? -xs[d + HD / 2] : xs[d - HD / 2];
    x[d] = xs[d] * cosf(fr) + rot * sinf(fr);
  }
  if (lane < HD - 64) {
    const int d = 64 + lane;
    const float fr = f[d];
    const float rot = (d < HD / 2) ? -xs[d + HD / 2] : xs[d - HD / 2];
    x[d] = xs[d] * cosf(fr) + rot * sinf(fr);
  }
}

// ---------------- attention: one block per (t, h) ----------------
__global__ __launch_bounds__(256) void attn_kernel(const float* __restrict__ qkv,
                                                   const int* __restrict__ cu,
                                                   int n_seq, int T,
                                                   float* __restrict__ attn_out) {
  const int t = blockIdx.x;
  const int h = blockIdx.y;
  const int tid = threadIdx.x;
  const int kvh = h >> 2;  // repeat_interleave: new head j -> old head j//4
  __shared__ float qs[HD];
  __shared__ float sc[MAXSEG];
  __shared__ float ks[CHUNK][HD + 1];  // +1 pad: stride 81 (coprime to 32) -> conflict-free
  __shared__ float psum[4][CHUNK];
  __shared__ float red[4];
  __shared__ int sb[2];
  if (tid == 0) {
    int s0 = 0, s1 = T;
    for (int i = 0; i < n_seq; ++i) {
      if (t >= cu[i] && t < cu[i + 1]) { s0 = cu[i]; s1 = cu[i + 1]; break; }
    }
    sb[0] = s0; sb[1] = s1;
  }
  if (tid < HD) qs[tid] = qkv[(size_t)t * QKV_ROW + h * HD + tid];
  __syncthreads();
  const int s0 = sb[0], len = sb[1] - sb[0];
  const float scale = 0.11180339887498949f;  // 1/sqrt(80)

  // ---- scores: chunked K staging, 4-way split dot ----
  for (int c = 0; c < len; c += CHUNK) {
    for (int jj = tid; jj < CHUNK * HD; jj += 256) {
      const int r = jj / HD, e = jj % HD;
      float v = 0.0f;
      if (c + r < len) v = qkv[(size_t)(s0 + c + r) * QKV_ROW + K_OFF + kvh * HD + e];
      ks[r][e] = v;
    }
    __syncthreads();
    {
      const int r = tid & 63, q = tid >> 6;
      float p = 0.0f;
      #pragma unroll
      for (int e = 0; e < 20; ++e) p += qs[q * 20 + e] * ks[r][q * 20 + e];
      psum[q][r] = p;
    }
    __syncthreads();
    if (tid < CHUNK && c + tid < len)
      sc[c + tid] = (psum[0][tid] + psum[1][tid] + psum[2][tid] + psum[3][tid]) * scale;
    __syncthreads();
  }

  // ---- softmax over sc[0..len) ----
  float lmax = -1e30f;
  for (int i = tid; i < len; i += 256) lmax = fmaxf(lmax, sc[i]);
  #pragma unroll
  for (int off = 32; off; off >>= 1) lmax = fmaxf(lmax, __shfl_down(lmax, off));
  if ((tid & 63) == 0) red[tid >> 6] = lmax;
  __syncthreads();
  const float m = fmaxf(fmaxf(red[0], red[1]), fmaxf(red[2], red[3]));
  __syncthreads();  // all reads of red done before reuse
  float lsum = 0.0f;
  for (int i = tid; i < len; i += 256) {
    const float p = __expf(sc[i] - m);
    sc[i] = p;
    lsum += p;
  }
  #pragma unroll
  for (int off = 32; off; off >>= 1) lsum += __shfl_down(lsum, off);
  if ((tid & 63) == 0) red[tid >> 6] = lsum;
  __syncthreads();
  const float S = red[0] + red[1] + red[2] + red[3];

  // ---- PV: threads 0..79 each own one output dim, coalesced V reads ----
  if (tid < HD) {
    float a0 = 0, a1 = 0, a2 = 0, a3 = 0;
    const float* vb = qkv + (size_t)s0 * QKV_ROW + V_OFF + kvh * HD + tid;
    int i = 0;
    for (; i + 3 < len; i += 4) {
      a0 += sc[i + 0] * vb[(size_t)(i + 0) * QKV_ROW];
      a1 += sc[i + 1] * vb[(size_t)(i + 1) * QKV_ROW];
      a2 += sc[i + 2] * vb[(size_t)(i + 2) * QKV_ROW];
      a3 += sc[i + 3] * vb[(size_t)(i + 3) * QKV_ROW];
    }
    for (; i < len; ++i) a0 += sc[i] * vb[(size_t)i * QKV_ROW];
    attn_out[(size_t)t * EMB + h * HD + tid] = (a0 + a1 + a2 + a3) / S;
  }
}

extern "C" void kernel_launch(void* const* d_in, const int* in_sizes, int n_in,
                              void* d_out, int out_size, void* d_ws, size_t ws_size,
                              hipStream_t stream) {
  const float* hidden = (const float*)d_in[0];
  const int*   cu     = (const int*)d_in[1];
  const float* rope   = (const float*)d_in[2];
  const float* w_qkv  = (const float*)d_in[3];
  const float* w_o    = (const float*)d_in[4];
  const float* qw     = (const float*)d_in[5];
  const float* kw     = (const float*)d_in[6];
  float* out = (float*)d_out;

  const int T = in_sizes[0] / EMB;       // 4096
  const int n_seq = in_sizes[1] - 1;     // 8

  float* qkv      = (float*)d_ws;                       // [T][1920]
  float* attn_buf = qkv + (size_t)T * QKV_ROW;          // [T][1280]

  // 1) qkv = hidden @ w_qkv^T   (M=T, N=1920, K=1280)
  gemm_rr<<<dim3(QKV_ROW / 64, T / 64), 256, 0, stream>>>(hidden, w_qkv, qkv, T, QKV_ROW, EMB);
  // 2) RMSNorm + RoPE on q and k heads, in place
  norm_rope_kernel<<<dim3(T, H_Q + H_KV), 64, 0, stream>>>(qkv, rope, qw, kw);
  // 3) block-diagonal GQA attention
  attn_kernel<<<dim3(T, H_Q), 256, 0, stream>>>(qkv, cu, n_seq, T, attn_buf);
  // 4) out = attn @ w_o^T       (M=T, N=1280, K=1280)
  gemm_rr<<<dim3(EMB / 64, T / 64), 256, 0, stream>>>(attn_buf, w_o, out, T, EMB, EMB);
}

// Round 2
// 404.965 us; speedup vs baseline: 14.9398x; 14.9398x over previous
//
#include <hip/hip_runtime.h>
#include <hip/hip_bf16.h>

#define H_Q 16
#define H_KV 4
#define HD 80
#define QKV_ROW 1920   // (16 + 2*4) * 80
#define K_OFF 1280     // 16*80
#define V_OFF 1600
#define EMB 1280
#define QT 64          // query tile rows
#define CK 32          // k/v chunk

typedef unsigned short u16;
typedef __attribute__((ext_vector_type(8))) short bf16x8;
typedef __attribute__((ext_vector_type(4))) float f32x4;

__device__ inline u16 f2bf(float f) {
  unsigned u = __float_as_uint(f);
  unsigned r = (u + 0x7FFFu + ((u >> 16) & 1u)) >> 16;
  return (u16)r;
}

// ---------------- fp32 -> bf16 conversion ----------------
__global__ __launch_bounds__(256) void cvt_bf16(const float* __restrict__ in,
                                                u16* __restrict__ out, int n) {
  int i = (blockIdx.x * 256 + threadIdx.x) * 4;
  if (i + 3 < n) {
    float4 v = *reinterpret_cast<const float4*>(in + i);
    ushort4 o;
    o.x = f2bf(v.x); o.y = f2bf(v.y); o.z = f2bf(v.z); o.w = f2bf(v.w);
    *reinterpret_cast<ushort4*>(out + i) = o;
  } else {
    for (; i < n; ++i) out[i] = f2bf(in[i]);
  }
}

// ---------------- token -> segment id ----------------
__global__ __launch_bounds__(256) void seg_kernel(const int* __restrict__ cu, int n_seq,
                                                  int T, int* __restrict__ seg) {
  int t = blockIdx.x * 256 + threadIdx.x;
  if (t < T) {
    int s = 0;
    for (int i = 1; i <= n_seq; ++i) s += (t >= cu[i]) ? 1 : 0;
    seg[t] = s;
  }
}

// ---------------- bf16 MFMA GEMM: C[M,N] = A[M,K] * B[N,K]^T, C fp32 ----------------
// 128x128 tile, 4 waves, each wave 64x64 via 4x4 16x16x32 fragments, BK=32.
__global__ __launch_bounds__(256) void gemm_bf16(const u16* __restrict__ A,
                                                 const u16* __restrict__ B,
                                                 float* __restrict__ C,
                                                 int M, int N, int K) {
  __shared__ u16 As[128 * 32];
  __shared__ u16 Bs[128 * 32];
  const int tid = threadIdx.x;
  const int bm = blockIdx.y * 128;
  const int bn = blockIdx.x * 128;
  const int w = tid >> 6;
  const int l = tid & 63;
  const int wr = (w >> 1) * 64, wc = (w & 1) * 64;
  const int fr = l & 15;   // fragment row (A) / col (B) / col (C)
  const int fq = l >> 4;   // quad
  const int arow = tid >> 2, acol = (tid & 3) * 8;

  f32x4 acc[4][4];
  #pragma unroll
  for (int mi = 0; mi < 4; ++mi)
    #pragma unroll
    for (int ni = 0; ni < 4; ++ni) acc[mi][ni] = (f32x4){0.f, 0.f, 0.f, 0.f};

  for (int k0 = 0; k0 < K; k0 += 32) {
    __syncthreads();
    #pragma unroll
    for (int it = 0; it < 2; ++it) {
      const u16* ga = A + (size_t)(bm + it * 64 + arow) * K + k0 + acol;
      __builtin_amdgcn_global_load_lds(
          (const __attribute__((address_space(1))) unsigned int*)ga,
          (__attribute__((address_space(3))) unsigned int*)&As[it * 2048 + tid * 8], 16, 0, 0);
      const u16* gb = B + (size_t)(bn + it * 64 + arow) * K + k0 + acol;
      __builtin_amdgcn_global_load_lds(
          (const __attribute__((address_space(1))) unsigned int*)gb,
          (__attribute__((address_space(3))) unsigned int*)&Bs[it * 2048 + tid * 8], 16, 0, 0);
    }
    __syncthreads();

    bf16x8 af[4], bfr[4];
    #pragma unroll
    for (int mi = 0; mi < 4; ++mi)
      af[mi] = *reinterpret_cast<const bf16x8*>(&As[(wr + mi * 16 + fr) * 32 + fq * 8]);
    #pragma unroll
    for (int ni = 0; ni < 4; ++ni)
      bfr[ni] = *reinterpret_cast<const bf16x8*>(&Bs[(wc + ni * 16 + fr) * 32 + fq * 8]);
    #pragma unroll
    for (int mi = 0; mi < 4; ++mi)
      #pragma unroll
      for (int ni = 0; ni < 4; ++ni)
        acc[mi][ni] = __builtin_amdgcn_mfma_f32_16x16x32_bf16(af[mi], bfr[ni], acc[mi][ni], 0, 0, 0);
  }

  #pragma unroll
  for (int mi = 0; mi < 4; ++mi)
    #pragma unroll
    for (int ni = 0; ni < 4; ++ni) {
      const int col = bn + wc + ni * 16 + fr;
      #pragma unroll
      for (int j = 0; j < 4; ++j) {
        const int row = bm + wr + mi * 16 + fq * 4 + j;
        C[(size_t)row * N + col] = acc[mi][ni][j];
      }
    }
}

// ---------------- per-head RMSNorm + RoPE (in place on q,k of qkv) ----------------
__global__ __launch_bounds__(64) void norm_rope_kernel(float* __restrict__ qkv,
                                                       const float* __restrict__ freqs,
                                                       const float* __restrict__ qw,
                                                       const float* __restrict__ kw) {
  const int t = blockIdx.x;
  const int h = blockIdx.y;
  const int lane = threadIdx.x;
  const bool is_q = (h < H_Q);
  float* x = qkv + (size_t)t * QKV_ROW + (is_q ? h * HD : K_OFF + (h - H_Q) * HD);
  const float* w = is_q ? qw : kw;
  float a = x[lane];
  float b = (lane < HD - 64) ? x[64 + lane] : 0.0f;
  float ss = a * a + b * b;
  #pragma unroll
  for (int off = 32; off; off >>= 1) ss += __shfl_down(ss, off);
  ss = __shfl(ss, 0);
  const float inv = rsqrtf(ss / (float)HD + 1e-6f);
  __shared__ float xs[HD];
  xs[lane] = a * inv * w[lane];
  if (lane < HD - 64) xs[64 + lane] = b * inv * w[64 + lane];
  __syncthreads();
  const float* f = freqs + (size_t)t * HD;
  {
    const int d = lane;
    const float fr = f[d];
    const float rot = (d < HD / 2) ? -xs[d + HD / 2] : xs[d - HD / 2];
    x[d] = xs[d] * __cosf(fr) + rot * __sinf(fr);
  }
  if (lane < HD - 64) {
    const int d = 64 + lane;
    const float fr = f[d];
    const float rot = (d < HD / 2) ? -xs[d + HD / 2] : xs[d - HD / 2];
    x[d] = xs[d] * __cosf(fr) + rot * __sinf(fr);
  }
}

// ---------------- tiled flash attention (fp32), bf16 output ----------------
// grid = (T/QT, H). block 256 = 16 ty x 16 tx. Thread owns 4 rows (ty*4+u), and
// per chunk 2 cols (tx*2+v) for S, 5 dims (tx*5+d) for PV output.
__global__ __launch_bounds__(256) void attn_v2(const float* __restrict__ qkv,
                                               const int* __restrict__ seg,
                                               const int* __restrict__ cu,
                                               int T,
                                               u16* __restrict__ attn_bf) {
  __shared__ float Qs[80][QT];      // Q^T, 20KB
  __shared__ float Ks[CK][81];      // K rows, 10.4KB
  __shared__ float Vs[CK][81];      // V rows, 10.4KB
  __shared__ float Ps[QT][CK + 1];  // probs, 8.4KB
  __shared__ int qsegs[QT];
  __shared__ int ksegs[CK];
  __shared__ int kranges[2];

  const int t0 = blockIdx.x * QT;
  const int h = blockIdx.y;
  const int kvh = h >> 2;
  const int tid = threadIdx.x;
  const int tx = tid & 15, ty = tid >> 4;

  for (int idx = tid; idx < 80 * QT; idx += 256) {
    const int r = idx / 80, e = idx % 80;
    Qs[e][r] = qkv[(size_t)(t0 + r) * QKV_ROW + h * HD + e];
  }
  if (tid < QT) qsegs[tid] = seg[t0 + tid];
  if (tid == 0) {
    kranges[0] = cu[seg[t0]];
    kranges[1] = cu[seg[t0 + QT - 1] + 1];
  }
  __syncthreads();
  const int kbeg = kranges[0], kend = kranges[1];
  int qsg[4];
  #pragma unroll
  for (int u = 0; u < 4; ++u) qsg[u] = qsegs[ty * 4 + u];

  float m_[4], l_[4], acc[4][5];
  #pragma unroll
  for (int u = 0; u < 4; ++u) {
    m_[u] = -1e30f; l_[u] = 0.f;
    #pragma unroll
    for (int d = 0; d < 5; ++d) acc[u][d] = 0.f;
  }
  const float scale = 0.11180339887498949f;  // 1/sqrt(80)

  for (int c = kbeg; c < kend; c += CK) {
    __syncthreads();  // prev PV done before restage
    for (int idx = tid; idx < 80 * CK; idx += 256) {
      const int r = idx / 80, e = idx % 80;
      float kv = 0.f, vv = 0.f;
      if (c + r < kend) {
        kv = qkv[(size_t)(c + r) * QKV_ROW + K_OFF + kvh * HD + e];
        vv = qkv[(size_t)(c + r) * QKV_ROW + V_OFF + kvh * HD + e];
      }
      Ks[r][e] = kv;
      Vs[r][e] = vv;
    }
    if (tid < CK) ksegs[tid] = (c + tid < kend) ? seg[c + tid] : -1;
    __syncthreads();

    // S tile: rows ty*4+u, cols tx*2+v
    float sacc[4][2] = {};
    for (int k = 0; k < 80; ++k) {
      const float4 q4 = *reinterpret_cast<const float4*>(&Qs[k][ty * 4]);
      const float k0v = Ks[tx * 2 + 0][k];
      const float k1v = Ks[tx * 2 + 1][k];
      sacc[0][0] += q4.x * k0v; sacc[0][1] += q4.x * k1v;
      sacc[1][0] += q4.y * k0v; sacc[1][1] += q4.y * k1v;
      sacc[2][0] += q4.z * k0v; sacc[2][1] += q4.z * k1v;
      sacc[3][0] += q4.w * k0v; sacc[3][1] += q4.w * k1v;
    }
    const int ks0 = ksegs[tx * 2], ks1 = ksegs[tx * 2 + 1];
    float p[4][2], alpha[4];
    #pragma unroll
    for (int u = 0; u < 4; ++u) {
      const float s0v = (qsg[u] == ks0) ? sacc[u][0] * scale : -1e30f;
      const float s1v = (qsg[u] == ks1) ? sacc[u][1] * scale : -1e30f;
      float mx = fmaxf(s0v, s1v);
      #pragma unroll
      for (int off = 1; off < 16; off <<= 1) mx = fmaxf(mx, __shfl_xor(mx, off));
      const float mn = fmaxf(m_[u], mx);
      alpha[u] = __expf(m_[u] - mn);          // m_==-1e30 & mn==-1e30 -> 1, harmless (l=acc=0)
      p[u][0] = (s0v > -1e29f) ? __expf(s0v - mn) : 0.f;
      p[u][1] = (s1v > -1e29f) ? __expf(s1v - mn) : 0.f;
      float rs = p[u][0] + p[u][1];
      #pragma unroll
      for (int off = 1; off < 16; off <<= 1) rs += __shfl_xor(rs, off);
      l_[u] = l_[u] * alpha[u] + rs;
      m_[u] = mn;
      #pragma unroll
      for (int d = 0; d < 5; ++d) acc[u][d] *= alpha[u];
      Ps[ty * 4 + u][tx * 2 + 0] = p[u][0];
      Ps[ty * 4 + u][tx * 2 + 1] = p[u][1];
    }
    __syncthreads();
    #pragma unroll 4
    for (int j = 0; j < CK; ++j) {
      float pv[4], vv[5];
      #pragma unroll
      for (int u = 0; u < 4; ++u) pv[u] = Ps[ty * 4 + u][j];
      #pragma unroll
      for (int d = 0; d < 5; ++d) vv[d] = Vs[j][tx * 5 + d];
      #pragma unroll
      for (int u = 0; u < 4; ++u)
        #pragma unroll
        for (int d = 0; d < 5; ++d) acc[u][d] += pv[u] * vv[d];
    }
  }

  #pragma unroll
  for (int u = 0; u < 4; ++u) {
    const float il = (l_[u] > 0.f) ? 1.0f / l_[u] : 0.f;
    #pragma unroll
    for (int d = 0; d < 5; ++d)
      attn_bf[(size_t)(t0 + ty * 4 + u) * EMB + h * HD + tx * 5 + d] = f2bf(acc[u][d] * il);
  }
}

extern "C" void kernel_launch(void* const* d_in, const int* in_sizes, int n_in,
                              void* d_out, int out_size, void* d_ws, size_t ws_size,
                              hipStream_t stream) {
  const float* hidden = (const float*)d_in[0];
  const int*   cu     = (const int*)d_in[1];
  const float* rope   = (const float*)d_in[2];
  const float* w_qkv  = (const float*)d_in[3];
  const float* w_o    = (const float*)d_in[4];
  const float* qw     = (const float*)d_in[5];
  const float* kw     = (const float*)d_in[6];
  float* out = (float*)d_out;

  const int T = in_sizes[0] / EMB;   // 4096
  const int n_seq = in_sizes[1] - 1; // 8

  // workspace layout (50.2 MB): qkv fp32 | hid_bf16 (reused as attn_bf16) | wqkv_bf | wo_bf | seg
  char* ws = (char*)d_ws;
  float* qkv   = (float*)ws;
  u16* hid_bf  = (u16*)(ws + (size_t)T * QKV_ROW * 4);
  u16* attn_bf = hid_bf;  // alias: hid_bf dead after qkv GEMM
  u16* wqkv_bf = hid_bf + (size_t)T * EMB;
  u16* wo_bf   = wqkv_bf + (size_t)QKV_ROW * EMB;
  int* segb    = (int*)(wo_bf + (size_t)EMB * EMB);

  const int n_hid = T * EMB, n_wqkv = QKV_ROW * EMB, n_wo = EMB * EMB;
  cvt_bf16<<<(n_hid / 4 + 255) / 256, 256, 0, stream>>>(hidden, hid_bf, n_hid);
  cvt_bf16<<<(n_wqkv / 4 + 255) / 256, 256, 0, stream>>>(w_qkv, wqkv_bf, n_wqkv);
  cvt_bf16<<<(n_wo / 4 + 255) / 256, 256, 0, stream>>>(w_o, wo_bf, n_wo);
  seg_kernel<<<(T + 255) / 256, 256, 0, stream>>>(cu, n_seq, T, segb);

  // qkv = hidden @ w_qkv^T  (M=T, N=1920, K=1280), fp32 out
  gemm_bf16<<<dim3(QKV_ROW / 128, T / 128), 256, 0, stream>>>(hid_bf, wqkv_bf, qkv, T, QKV_ROW, EMB);
  norm_rope_kernel<<<dim3(T, H_Q + H_KV), 64, 0, stream>>>(qkv, rope, qw, kw);
  attn_v2<<<dim3(T / QT, H_Q), 256, 0, stream>>>(qkv, segb, cu, T, attn_bf);
  // out = attn @ w_o^T  (M=T, N=1280, K=1280)
  gemm_bf16<<<dim3(EMB / 128, T / 128), 256, 0, stream>>>(attn_bf, wo_bf, out, T, EMB, EMB);
}

// Round 3
// 196.913 us; speedup vs baseline: 30.7246x; 2.0566x over previous
//
#include <hip/hip_runtime.h>
#include <hip/hip_bf16.h>

#define H_Q 16
#define H_KV 4
#define HD 80
#define QKV_ROW 1920   // (16 + 2*4) * 80
#define K_OFF 1280     // 16*80
#define V_OFF 1600
#define EMB 1280
#define KC 64          // k/v chunk rows
#define KSTR 104       // K_lds row stride (u16): 96 data+pad, 208B = 16B-mult, 2-way banks
#define VSTR 72        // V^T / P row stride (u16): 144B

typedef unsigned short u16;
typedef __attribute__((ext_vector_type(8))) short bf16x8;
typedef __attribute__((ext_vector_type(4))) float f32x4;

__device__ inline u16 f2bf(float f) {
  unsigned u = __float_as_uint(f);
  unsigned r = (u + 0x7FFFu + ((u >> 16) & 1u)) >> 16;
  return (u16)r;
}
__device__ inline float bf2f(u16 v) { return __uint_as_float(((unsigned)v) << 16); }

// ---------------- fp32 -> bf16 conversion ----------------
__global__ __launch_bounds__(256) void cvt_bf16(const float* __restrict__ in,
                                                u16* __restrict__ out, int n) {
  int i = (blockIdx.x * 256 + threadIdx.x) * 4;
  if (i + 3 < n) {
    float4 v = *reinterpret_cast<const float4*>(in + i);
    ushort4 o;
    o.x = f2bf(v.x); o.y = f2bf(v.y); o.z = f2bf(v.z); o.w = f2bf(v.w);
    *reinterpret_cast<ushort4*>(out + i) = o;
  } else {
    for (; i < n; ++i) out[i] = f2bf(in[i]);
  }
}

// ---------------- token -> segment id ----------------
__global__ __launch_bounds__(256) void seg_kernel(const int* __restrict__ cu, int n_seq,
                                                  int T, int* __restrict__ seg) {
  int t = blockIdx.x * 256 + threadIdx.x;
  if (t < T) {
    int s = 0;
    for (int i = 1; i <= n_seq; ++i) s += (t >= cu[i]) ? 1 : 0;
    seg[t] = s;
  }
}

// ---------------- bf16 MFMA GEMM: C[M,N] = A[M,K] * B[N,K]^T ----------------
// 128x128 tile, 4 waves, each wave 64x64 via 4x4 16x16x32 fragments, BK=32.
template <typename OUT>
__global__ __launch_bounds__(256) void gemm_bf16(const u16* __restrict__ A,
                                                 const u16* __restrict__ B,
                                                 OUT* __restrict__ C,
                                                 int M, int N, int K) {
  __shared__ u16 As[128 * 32];
  __shared__ u16 Bs[128 * 32];
  const int tid = threadIdx.x;
  const int bm = blockIdx.y * 128;
  const int bn = blockIdx.x * 128;
  const int w = tid >> 6;
  const int l = tid & 63;
  const int wr = (w >> 1) * 64, wc = (w & 1) * 64;
  const int fr = l & 15;
  const int fq = l >> 4;
  const int arow = tid >> 2, acol = (tid & 3) * 8;

  f32x4 acc[4][4];
  #pragma unroll
  for (int mi = 0; mi < 4; ++mi)
    #pragma unroll
    for (int ni = 0; ni < 4; ++ni) acc[mi][ni] = (f32x4){0.f, 0.f, 0.f, 0.f};

  for (int k0 = 0; k0 < K; k0 += 32) {
    __syncthreads();
    #pragma unroll
    for (int it = 0; it < 2; ++it) {
      const u16* ga = A + (size_t)(bm + it * 64 + arow) * K + k0 + acol;
      __builtin_amdgcn_global_load_lds(
          (const __attribute__((address_space(1))) unsigned int*)ga,
          (__attribute__((address_space(3))) unsigned int*)&As[it * 2048 + tid * 8], 16, 0, 0);
      const u16* gb = B + (size_t)(bn + it * 64 + arow) * K + k0 + acol;
      __builtin_amdgcn_global_load_lds(
          (const __attribute__((address_space(1))) unsigned int*)gb,
          (__attribute__((address_space(3))) unsigned int*)&Bs[it * 2048 + tid * 8], 16, 0, 0);
    }
    __syncthreads();

    bf16x8 af[4], bfr[4];
    #pragma unroll
    for (int mi = 0; mi < 4; ++mi)
      af[mi] = *reinterpret_cast<const bf16x8*>(&As[(wr + mi * 16 + fr) * 32 + fq * 8]);
    #pragma unroll
    for (int ni = 0; ni < 4; ++ni)
      bfr[ni] = *reinterpret_cast<const bf16x8*>(&Bs[(wc + ni * 16 + fr) * 32 + fq * 8]);
    #pragma unroll
    for (int mi = 0; mi < 4; ++mi)
      #pragma unroll
      for (int ni = 0; ni < 4; ++ni)
        acc[mi][ni] = __builtin_amdgcn_mfma_f32_16x16x32_bf16(af[mi], bfr[ni], acc[mi][ni], 0, 0, 0);
  }

  #pragma unroll
  for (int mi = 0; mi < 4; ++mi)
    #pragma unroll
    for (int ni = 0; ni < 4; ++ni) {
      const int col = bn + wc + ni * 16 + fr;
      #pragma unroll
      for (int j = 0; j < 4; ++j) {
        const int row = bm + wr + mi * 16 + fq * 4 + j;
        if constexpr (sizeof(OUT) == 2)
          C[(size_t)row * N + col] = f2bf(acc[mi][ni][j]);
        else
          C[(size_t)row * N + col] = acc[mi][ni][j];
      }
    }
}

// ---------------- per-head RMSNorm + RoPE, in place on bf16 qkv ----------------
__global__ __launch_bounds__(64) void norm_rope_bf(u16* __restrict__ qkv,
                                                   const float* __restrict__ freqs,
                                                   const float* __restrict__ qw,
                                                   const float* __restrict__ kw) {
  const int t = blockIdx.x;
  const int h = blockIdx.y;
  const int lane = threadIdx.x;
  const bool is_q = (h < H_Q);
  u16* x = qkv + (size_t)t * QKV_ROW + (is_q ? h * HD : K_OFF + (h - H_Q) * HD);
  const float* w = is_q ? qw : kw;
  float a = bf2f(x[lane]);
  float b = (lane < HD - 64) ? bf2f(x[64 + lane]) : 0.0f;
  float ss = a * a + b * b;
  #pragma unroll
  for (int off = 32; off; off >>= 1) ss += __shfl_down(ss, off);
  ss = __shfl(ss, 0);
  const float inv = rsqrtf(ss / (float)HD + 1e-6f);
  __shared__ float xs[HD];
  xs[lane] = a * inv * w[lane];
  if (lane < HD - 64) xs[64 + lane] = b * inv * w[64 + lane];
  __syncthreads();
  const float* f = freqs + (size_t)t * HD;
  {
    const int d = lane;
    const float fr = f[d];
    const float rot = (d < HD / 2) ? -xs[d + HD / 2] : xs[d - HD / 2];
    x[d] = f2bf(xs[d] * __cosf(fr) + rot * __sinf(fr));
  }
  if (lane < HD - 64) {
    const int d = 64 + lane;
    const float fr = f[d];
    const float rot = (d < HD / 2) ? -xs[d + HD / 2] : xs[d - HD / 2];
    x[d] = f2bf(xs[d] * __cosf(fr) + rot * __sinf(fr));
  }
}

// ---------------- MFMA flash attention ----------------
// grid (T/64, 16). 4 waves; wave w owns q rows t0+w*16 .. +15.
__global__ __launch_bounds__(256) void attn_v3(const u16* __restrict__ qkv,
                                               const int* __restrict__ seg,
                                               const int* __restrict__ cu,
                                               int T,
                                               u16* __restrict__ attn_bf) {
  __shared__ u16 K_lds[KC * KSTR];    // [k][e], e 0..79 data, 80..95 zeroed
  __shared__ u16 V_lds[HD * VSTR];    // V^T: [d][k]
  __shared__ u16 P_lds[64 * VSTR];    // [q][k], wave-private rows
  __shared__ int ksegs[KC];
  __shared__ int kranges[2];

  const int t0 = blockIdx.x * 64;
  const int h = blockIdx.y;
  const int kvh = h >> 2;
  const int tid = threadIdx.x;
  const int w = tid >> 6, l = tid & 63;
  const int g = l >> 4, fr = l & 15;

  // zero K_lds pad cols 80..95 (u32 idx 40..47 per row) once
  for (int i = tid; i < KC * 8; i += 256)
    ((unsigned*)K_lds)[(i >> 3) * (KSTR / 2) + 40 + (i & 7)] = 0;
  if (tid == 0) {
    kranges[0] = cu[seg[t0]];
    kranges[1] = cu[seg[t0 + 63] + 1];
  }

  // Q fragments (registers, hoisted). e padded 80->96 with zeros.
  const int qrow = t0 + w * 16 + fr;
  const u16* qp = qkv + (size_t)qrow * QKV_ROW + h * HD;
  bf16x8 qa0 = *reinterpret_cast<const bf16x8*>(qp + g * 8);
  bf16x8 qa1 = *reinterpret_cast<const bf16x8*>(qp + 32 + g * 8);
  bf16x8 qa2 = (g < 2) ? *reinterpret_cast<const bf16x8*>(qp + 64 + g * 8)
                       : (bf16x8)(short)0;
  const int qr0 = t0 + w * 16 + g * 4;
  int qsg[4];
  #pragma unroll
  for (int j = 0; j < 4; ++j) qsg[j] = seg[qr0 + j];

  float m_[4], l_[4];
  f32x4 acc[5];
  #pragma unroll
  for (int j = 0; j < 4; ++j) { m_[j] = -1e30f; l_[j] = 0.f; }
  #pragma unroll
  for (int dt = 0; dt < 5; ++dt) acc[dt] = (f32x4){0.f, 0.f, 0.f, 0.f};
  const float scale = 0.11180339887498949f;  // 1/sqrt(80)

  __syncthreads();
  const int kbeg = kranges[0], kend = kranges[1];

  for (int c = kbeg; c < kend; c += KC) {
    __syncthreads();  // prev PV reads done before restage
    // stage K rows (u32, coalesced, conflict-free)
    for (int i = tid; i < KC * 40; i += 256) {
      const int r = i / 40, cc = i % 40;
      unsigned v = 0;
      if (c + r < kend)
        v = reinterpret_cast<const unsigned*>(qkv + (size_t)(c + r) * QKV_ROW + K_OFF + kvh * HD)[cc];
      reinterpret_cast<unsigned*>(K_lds)[r * (KSTR / 2) + cc] = v;
    }
    // stage V transposed (u32 global read; 2 scalar u16 LDS writes)
    for (int i = tid; i < KC * 40; i += 256) {
      const int r = i / 40, dp = i % 40;
      unsigned v = 0;
      if (c + r < kend)
        v = reinterpret_cast<const unsigned*>(qkv + (size_t)(c + r) * QKV_ROW + V_OFF + kvh * HD)[dp];
      V_lds[(2 * dp) * VSTR + r] = (u16)v;
      V_lds[(2 * dp + 1) * VSTR + r] = (u16)(v >> 16);
    }
    if (tid < KC) ksegs[tid] = (c + tid < kend) ? seg[c + tid] : -1;
    __syncthreads();

    // ---- S = Q K^T : 4 k-tiles of 16 ----
    f32x4 sacc[4];
    #pragma unroll
    for (int f = 0; f < 4; ++f) {
      const u16* kp = &K_lds[(f * 16 + fr) * KSTR];
      bf16x8 b0 = *reinterpret_cast<const bf16x8*>(kp + g * 8);
      bf16x8 b1 = *reinterpret_cast<const bf16x8*>(kp + 32 + g * 8);
      bf16x8 b2 = *reinterpret_cast<const bf16x8*>(kp + 64 + g * 8);  // 64..95 incl pad
      f32x4 s = (f32x4){0.f, 0.f, 0.f, 0.f};
      s = __builtin_amdgcn_mfma_f32_16x16x32_bf16(qa0, b0, s, 0, 0, 0);
      s = __builtin_amdgcn_mfma_f32_16x16x32_bf16(qa1, b1, s, 0, 0, 0);
      s = __builtin_amdgcn_mfma_f32_16x16x32_bf16(qa2, b2, s, 0, 0, 0);
      sacc[f] = s;
    }

    // ---- mask + online softmax (lane rows g*4+j, cols f*16+fr) ----
    int ks[4];
    #pragma unroll
    for (int f = 0; f < 4; ++f) ks[f] = ksegs[f * 16 + fr];
    #pragma unroll
    for (int j = 0; j < 4; ++j) {
      float sv[4];
      #pragma unroll
      for (int f = 0; f < 4; ++f)
        sv[f] = (qsg[j] == ks[f]) ? sacc[f][j] * scale : -1e30f;
      float mj = fmaxf(fmaxf(sv[0], sv[1]), fmaxf(sv[2], sv[3]));
      #pragma unroll
      for (int off = 1; off < 16; off <<= 1) mj = fmaxf(mj, __shfl_xor(mj, off));
      const float mn = fmaxf(m_[j], mj);
      const float al = __expf(m_[j] - mn);
      float rs = 0.f;
      u16 pb[4];
      #pragma unroll
      for (int f = 0; f < 4; ++f) {
        const float p = (sv[f] > -1e29f) ? __expf(sv[f] - mn) : 0.f;
        rs += p;
        pb[f] = f2bf(p);
      }
      #pragma unroll
      for (int off = 1; off < 16; off <<= 1) rs += __shfl_xor(rs, off);
      l_[j] = l_[j] * al + rs;
      m_[j] = mn;
      #pragma unroll
      for (int dt = 0; dt < 5; ++dt) acc[dt][j] *= al;
      const int prow = w * 16 + g * 4 + j;
      #pragma unroll
      for (int f = 0; f < 4; ++f) P_lds[prow * VSTR + f * 16 + fr] = pb[f];
    }

    // ---- PV (wave-private P rows; compiler inserts lgkmcnt for ds RAW) ----
    const u16* pp = &P_lds[(w * 16 + fr) * VSTR];
    bf16x8 pa0 = *reinterpret_cast<const bf16x8*>(pp + g * 8);
    bf16x8 pa1 = *reinterpret_cast<const bf16x8*>(pp + 32 + g * 8);
    #pragma unroll
    for (int dt = 0; dt < 5; ++dt) {
      const u16* vp = &V_lds[(dt * 16 + fr) * VSTR];
      bf16x8 vb0 = *reinterpret_cast<const bf16x8*>(vp + g * 8);
      bf16x8 vb1 = *reinterpret_cast<const bf16x8*>(vp + 32 + g * 8);
      acc[dt] = __builtin_amdgcn_mfma_f32_16x16x32_bf16(pa0, vb0, acc[dt], 0, 0, 0);
      acc[dt] = __builtin_amdgcn_mfma_f32_16x16x32_bf16(pa1, vb1, acc[dt], 0, 0, 0);
    }
  }

  // ---- epilogue: O = acc / l ----
  #pragma unroll
  for (int j = 0; j < 4; ++j) {
    const float il = (l_[j] > 0.f) ? 1.0f / l_[j] : 0.f;
    const int row = t0 + w * 16 + g * 4 + j;
    #pragma unroll
    for (int dt = 0; dt < 5; ++dt)
      attn_bf[(size_t)row * EMB + h * HD + dt * 16 + fr] = f2bf(acc[dt][j] * il);
  }
}

extern "C" void kernel_launch(void* const* d_in, const int* in_sizes, int n_in,
                              void* d_out, int out_size, void* d_ws, size_t ws_size,
                              hipStream_t stream) {
  const float* hidden = (const float*)d_in[0];
  const int*   cu     = (const int*)d_in[1];
  const float* rope   = (const float*)d_in[2];
  const float* w_qkv  = (const float*)d_in[3];
  const float* w_o    = (const float*)d_in[4];
  const float* qw     = (const float*)d_in[5];
  const float* kw     = (const float*)d_in[6];
  float* out = (float*)d_out;

  const int T = in_sizes[0] / EMB;   // 4096
  const int n_seq = in_sizes[1] - 1; // 8

  // workspace (~34.4MB): qkv_bf | hid_bf(=attn_bf alias) | wqkv_bf | wo_bf | seg
  u16* qkv_bf  = (u16*)d_ws;
  u16* hid_bf  = qkv_bf + (size_t)T * QKV_ROW;
  u16* attn_bf = hid_bf;  // alias: hid_bf dead after qkv GEMM
  u16* wqkv_bf = hid_bf + (size_t)T * EMB;
  u16* wo_bf   = wqkv_bf + (size_t)QKV_ROW * EMB;
  int* segb    = (int*)(wo_bf + (size_t)EMB * EMB);

  const int n_hid = T * EMB, n_wqkv = QKV_ROW * EMB, n_wo = EMB * EMB;
  cvt_bf16<<<(n_hid / 4 + 255) / 256, 256, 0, stream>>>(hidden, hid_bf, n_hid);
  cvt_bf16<<<(n_wqkv / 4 + 255) / 256, 256, 0, stream>>>(w_qkv, wqkv_bf, n_wqkv);
  cvt_bf16<<<(n_wo / 4 + 255) / 256, 256, 0, stream>>>(w_o, wo_bf, n_wo);
  seg_kernel<<<(T + 255) / 256, 256, 0, stream>>>(cu, n_seq, T, segb);

  // qkv = hidden @ w_qkv^T  (bf16 out)
  gemm_bf16<u16><<<dim3(QKV_ROW / 128, T / 128), 256, 0, stream>>>(hid_bf, wqkv_bf, qkv_bf, T, QKV_ROW, EMB);
  norm_rope_bf<<<dim3(T, H_Q + H_KV), 64, 0, stream>>>(qkv_bf, rope, qw, kw);
  attn_v3<<<dim3(T / 64, H_Q), 256, 0, stream>>>(qkv_bf, segb, cu, T, attn_bf);
  // out = attn @ w_o^T  (fp32 out)
  gemm_bf16<float><<<dim3(EMB / 128, T / 128), 256, 0, stream>>>(attn_bf, wo_bf, out, T, EMB, EMB);
}

// Round 4
// 155.243 us; speedup vs baseline: 38.9717x; 1.2684x over previous
//
#include <hip/hip_runtime.h>
#include <hip/hip_bf16.h>

#define H_Q 16
#define H_KV 4
#define HD 80
#define QKV_ROW 1920   // (16 + 2*4) * 80
#define K_OFF 1280     // 16*80
#define V_OFF 1600
#define EMB 1280
#define QT 128         // query tile rows (8 waves)
#define KC 64          // k/v chunk rows
#define KSTR 104       // K_lds row stride (u16): 96 data+pad, 208B
#define VSTR 72        // V^T / P row stride (u16): 144B

typedef unsigned short u16;
typedef unsigned int u32;
typedef __attribute__((ext_vector_type(8))) short bf16x8;
typedef __attribute__((ext_vector_type(4))) float f32x4;

__device__ inline u16 f2bf(float f) {
  unsigned u = __float_as_uint(f);
  unsigned r = (u + 0x7FFFu + ((u >> 16) & 1u)) >> 16;
  return (u16)r;
}
__device__ inline float bf2f(u16 v) { return __uint_as_float(((unsigned)v) << 16); }

// ---------------- fp32 -> bf16 conversion ----------------
__global__ __launch_bounds__(256) void cvt_bf16(const float* __restrict__ in,
                                                u16* __restrict__ out, int n) {
  int i = (blockIdx.x * 256 + threadIdx.x) * 4;
  if (i + 3 < n) {
    float4 v = *reinterpret_cast<const float4*>(in + i);
    ushort4 o;
    o.x = f2bf(v.x); o.y = f2bf(v.y); o.z = f2bf(v.z); o.w = f2bf(v.w);
    *reinterpret_cast<ushort4*>(out + i) = o;
  } else {
    for (; i < n; ++i) out[i] = f2bf(in[i]);
  }
}

// ---------------- token -> segment id ----------------
__global__ __launch_bounds__(256) void seg_kernel(const int* __restrict__ cu, int n_seq,
                                                  int T, int* __restrict__ seg) {
  int t = blockIdx.x * 256 + threadIdx.x;
  if (t < T) {
    int s = 0;
    for (int i = 1; i <= n_seq; ++i) s += (t >= cu[i]) ? 1 : 0;
    seg[t] = s;
  }
}

// ---------------- bf16 MFMA GEMM: C[M,N] = A[M,K] * B[N,K]^T ----------------
// 128x128 tile, 4 waves, 2-phase double-buffered LDS, 1D grid + XCD swizzle.
template <typename OUT>
__global__ __launch_bounds__(256) void gemm_bf16(const u16* __restrict__ A,
                                                 const u16* __restrict__ B,
                                                 OUT* __restrict__ C,
                                                 int M, int N, int K,
                                                 int gx, int nwg) {
  __shared__ u16 As[2][128 * 32];
  __shared__ u16 Bs[2][128 * 32];
  const int tid = threadIdx.x;
  // bijective XCD swizzle (launcher guarantees nwg % 8 == 0)
  const int id = blockIdx.x;
  const int sw = (id & 7) * (nwg >> 3) + (id >> 3);
  const int bm = (sw / gx) * 128;
  const int bn = (sw % gx) * 128;
  const int w = tid >> 6;
  const int l = tid & 63;
  const int wr = (w >> 1) * 64, wc = (w & 1) * 64;
  const int fr = l & 15;
  const int fq = l >> 4;
  const int arow = tid >> 2, acol = (tid & 3) * 8;

  f32x4 acc[4][4];
  #pragma unroll
  for (int mi = 0; mi < 4; ++mi)
    #pragma unroll
    for (int ni = 0; ni < 4; ++ni) acc[mi][ni] = (f32x4){0.f, 0.f, 0.f, 0.f};

  #define STAGE(buf, k0)                                                              \
    do {                                                                              \
      _Pragma("unroll")                                                               \
      for (int it = 0; it < 2; ++it) {                                                \
        const u16* ga = A + (size_t)(bm + it * 64 + arow) * K + (k0) + acol;          \
        __builtin_amdgcn_global_load_lds(                                             \
            (const __attribute__((address_space(1))) unsigned int*)ga,                \
            (__attribute__((address_space(3))) unsigned int*)&As[buf][it * 2048 + tid * 8], 16, 0, 0); \
        const u16* gb = B + (size_t)(bn + it * 64 + arow) * K + (k0) + acol;          \
        __builtin_amdgcn_global_load_lds(                                             \
            (const __attribute__((address_space(1))) unsigned int*)gb,                \
            (__attribute__((address_space(3))) unsigned int*)&Bs[buf][it * 2048 + tid * 8], 16, 0, 0); \
      }                                                                               \
    } while (0)

  const int nt = K >> 5;
  STAGE(0, 0);
  __syncthreads();  // drains vmcnt -> buf0 ready

  for (int t = 0; t < nt; ++t) {
    const int cur = t & 1;
    if (t + 1 < nt) STAGE(cur ^ 1, (t + 1) * 32);  // overlap with compute below

    bf16x8 af[4], bfr[4];
    #pragma unroll
    for (int mi = 0; mi < 4; ++mi)
      af[mi] = *reinterpret_cast<const bf16x8*>(&As[cur][(wr + mi * 16 + fr) * 32 + fq * 8]);
    #pragma unroll
    for (int ni = 0; ni < 4; ++ni)
      bfr[ni] = *reinterpret_cast<const bf16x8*>(&Bs[cur][(wc + ni * 16 + fr) * 32 + fq * 8]);
    #pragma unroll
    for (int mi = 0; mi < 4; ++mi)
      #pragma unroll
      for (int ni = 0; ni < 4; ++ni)
        acc[mi][ni] = __builtin_amdgcn_mfma_f32_16x16x32_bf16(af[mi], bfr[ni], acc[mi][ni], 0, 0, 0);

    __syncthreads();  // waits next-tile loads (issued before compute) + ds_reads done
  }
  #undef STAGE

  #pragma unroll
  for (int mi = 0; mi < 4; ++mi)
    #pragma unroll
    for (int ni = 0; ni < 4; ++ni) {
      const int col = bn + wc + ni * 16 + fr;
      #pragma unroll
      for (int j = 0; j < 4; ++j) {
        const int row = bm + wr + mi * 16 + fq * 4 + j;
        if constexpr (sizeof(OUT) == 2)
          C[(size_t)row * N + col] = f2bf(acc[mi][ni][j]);
        else
          C[(size_t)row * N + col] = acc[mi][ni][j];
      }
    }
}

// ---------------- per-head RMSNorm + RoPE, in place on bf16 qkv ----------------
// grid (T, 5), block 256: wave w handles head blockIdx.y*4 + w.
__global__ __launch_bounds__(256) void norm_rope_bf(u16* __restrict__ qkv,
                                                    const float* __restrict__ freqs,
                                                    const float* __restrict__ qw,
                                                    const float* __restrict__ kw) {
  const int t = blockIdx.x;
  const int w = threadIdx.x >> 6;
  const int h = blockIdx.y * 4 + w;
  const int lane = threadIdx.x & 63;
  const bool is_q = (h < H_Q);
  u16* x = qkv + (size_t)t * QKV_ROW + (is_q ? h * HD : K_OFF + (h - H_Q) * HD);
  const float* wt = is_q ? qw : kw;
  float a = bf2f(x[lane]);
  float b = (lane < HD - 64) ? bf2f(x[64 + lane]) : 0.0f;
  float ss = a * a + b * b;
  #pragma unroll
  for (int off = 32; off; off >>= 1) ss += __shfl_down(ss, off);
  ss = __shfl(ss, 0);
  const float inv = rsqrtf(ss / (float)HD + 1e-6f);
  __shared__ float xs[4][HD];
  xs[w][lane] = a * inv * wt[lane];
  if (lane < HD - 64) xs[w][64 + lane] = b * inv * wt[64 + lane];
  __syncthreads();
  const float* f = freqs + (size_t)t * HD;
  {
    const int d = lane;
    const float fr = f[d];
    const float rot = (d < HD / 2) ? -xs[w][d + HD / 2] : xs[w][d - HD / 2];
    x[d] = f2bf(xs[w][d] * __cosf(fr) + rot * __sinf(fr));
  }
  if (lane < HD - 64) {
    const int d = 64 + lane;
    const float fr = f[d];
    const float rot = (d < HD / 2) ? -xs[w][d + HD / 2] : xs[w][d - HD / 2];
    x[d] = f2bf(xs[w][d] * __cosf(fr) + rot * __sinf(fr));
  }
}

// ---------------- MFMA flash attention v4 ----------------
// grid (T/QT, 16), 8 waves; wave w owns q rows t0+w*16..+15.
// Row-sum via ones-column MFMA; defer-rescale (THR=8); mask-free fast path.
__global__ __launch_bounds__(512) void attn_v4(const u16* __restrict__ qkv,
                                               const int* __restrict__ seg,
                                               const int* __restrict__ cu,
                                               int T,
                                               u16* __restrict__ attn_bf) {
  __shared__ u16 K_lds[KC * KSTR];      // [k][e], e 0..79 data, 80..95 zeroed
  __shared__ u16 V_lds[96 * VSTR];      // V^T [d][k]; row 80 = 1.0, 81..95 = 0
  __shared__ u16 P_lds[QT * VSTR];      // [q][k], wave-private rows
  __shared__ int ksegs[KC];
  __shared__ int kranges[2];

  const int t0 = blockIdx.x * QT;
  const int h = blockIdx.y;
  const int kvh = h >> 2;
  const int tid = threadIdx.x;
  const int w = tid >> 6, l = tid & 63;
  const int g = l >> 4, fr = l & 15;

  // zero K_lds pad cols 80..95 (u32 idx 40..47 per row), once
  for (int i = tid; i < KC * 8; i += 512)
    ((u32*)K_lds)[(i >> 3) * (KSTR / 2) + 40 + (i & 7)] = 0;
  // ones/zero rows 80..95 of V^T, once
  for (int i = tid; i < 16 * (VSTR / 2); i += 512) {
    const int r = 80 + i / (VSTR / 2), c = i % (VSTR / 2);
    ((u32*)V_lds)[r * (VSTR / 2) + c] = (r == 80) ? 0x3f803f80u : 0u;
  }
  if (tid == 0) {
    kranges[0] = cu[seg[t0]];
    kranges[1] = cu[seg[t0 + QT - 1] + 1];
  }

  // Q fragments (registers). e padded 80->96 with zeros.
  const int qrow = t0 + w * 16 + fr;
  const u16* qp = qkv + (size_t)qrow * QKV_ROW + h * HD;
  bf16x8 qa0 = *reinterpret_cast<const bf16x8*>(qp + g * 8);
  bf16x8 qa1 = *reinterpret_cast<const bf16x8*>(qp + 32 + g * 8);
  bf16x8 qa2 = (g < 2) ? *reinterpret_cast<const bf16x8*>(qp + 64 + g * 8)
                       : (bf16x8)(short)0;
  const int qr0 = t0 + w * 16 + g * 4;
  int qsg[4];
  #pragma unroll
  for (int j = 0; j < 4; ++j) qsg[j] = seg[qr0 + j];

  float m_[4];
  f32x4 acc[6];
  #pragma unroll
  for (int j = 0; j < 4; ++j) m_[j] = -1e30f;
  #pragma unroll
  for (int dt = 0; dt < 6; ++dt) acc[dt] = (f32x4){0.f, 0.f, 0.f, 0.f};
  const float scale = 0.11180339887498949f;  // 1/sqrt(80)

  __syncthreads();
  const int kbeg = kranges[0], kend = kranges[1];
  // fast path: whole q-tile in one segment, k-range a multiple of KC -> no masking
  const bool fast = (seg[t0] == seg[t0 + QT - 1]) && (((kend - kbeg) & (KC - 1)) == 0);

  for (int c = kbeg; c < kend; c += KC) {
    __syncthreads();  // prev PV reads done before restage
    // stage K rows (u32, coalesced, conflict-free)
    for (int i = tid; i < KC * 40; i += 512) {
      const int r = i / 40, cc = i % 40;
      u32 v = 0;
      if (c + r < kend)
        v = reinterpret_cast<const u32*>(qkv + (size_t)(c + r) * QKV_ROW + K_OFF + kvh * HD)[cc];
      ((u32*)K_lds)[r * (KSTR / 2) + cc] = v;
    }
    // stage V transposed
    for (int i = tid; i < KC * 40; i += 512) {
      const int r = i / 40, dp = i % 40;
      u32 v = 0;
      if (c + r < kend)
        v = reinterpret_cast<const u32*>(qkv + (size_t)(c + r) * QKV_ROW + V_OFF + kvh * HD)[dp];
      V_lds[(2 * dp) * VSTR + r] = (u16)v;
      V_lds[(2 * dp + 1) * VSTR + r] = (u16)(v >> 16);
    }
    if (!fast && tid < KC) ksegs[tid] = (c + tid < kend) ? seg[c + tid] : -1;
    __syncthreads();

    // ---- S = Q K^T ----
    f32x4 sacc[4];
    #pragma unroll
    for (int f = 0; f < 4; ++f) {
      const u16* kp = &K_lds[(f * 16 + fr) * KSTR];
      bf16x8 b0 = *reinterpret_cast<const bf16x8*>(kp + g * 8);
      bf16x8 b1 = *reinterpret_cast<const bf16x8*>(kp + 32 + g * 8);
      bf16x8 b2 = *reinterpret_cast<const bf16x8*>(kp + 64 + g * 8);
      f32x4 s = (f32x4){0.f, 0.f, 0.f, 0.f};
      s = __builtin_amdgcn_mfma_f32_16x16x32_bf16(qa0, b0, s, 0, 0, 0);
      s = __builtin_amdgcn_mfma_f32_16x16x32_bf16(qa1, b1, s, 0, 0, 0);
      s = __builtin_amdgcn_mfma_f32_16x16x32_bf16(qa2, b2, s, 0, 0, 0);
      sacc[f] = s;
    }

    // ---- online softmax, defer-rescale ----
    int ks[4];
    if (!fast) {
      #pragma unroll
      for (int f = 0; f < 4; ++f) ks[f] = ksegs[f * 16 + fr];
    }
    #pragma unroll
    for (int j = 0; j < 4; ++j) {
      float sv[4];
      #pragma unroll
      for (int f = 0; f < 4; ++f) {
        sv[f] = sacc[f][j] * scale;
        if (!fast && qsg[j] != ks[f]) sv[f] = -1e30f;
      }
      float mj = fmaxf(fmaxf(sv[0], sv[1]), fmaxf(sv[2], sv[3]));
      #pragma unroll
      for (int off = 1; off < 16; off <<= 1) mj = fmaxf(mj, __shfl_xor(mj, off));
      if (mj > m_[j] + 8.f) {  // defer-rescale: skip when growth <= 8
        const float al = __expf(m_[j] - mj);
        m_[j] = mj;
        #pragma unroll
        for (int dt = 0; dt < 6; ++dt) acc[dt][j] *= al;
      }
      const int prow = w * 16 + g * 4 + j;
      #pragma unroll
      for (int f = 0; f < 4; ++f) {
        const float p = (sv[f] > -1e29f) ? __expf(sv[f] - m_[j]) : 0.f;
        P_lds[prow * VSTR + f * 16 + fr] = f2bf(p);
      }
    }

    // ---- PV (+ ones-column row-sum in dt=5) ----
    const u16* pp = &P_lds[(w * 16 + fr) * VSTR];
    bf16x8 pa0 = *reinterpret_cast<const bf16x8*>(pp + g * 8);
    bf16x8 pa1 = *reinterpret_cast<const bf16x8*>(pp + 32 + g * 8);
    #pragma unroll
    for (int dt = 0; dt < 6; ++dt) {
      const u16* vp = &V_lds[(dt * 16 + fr) * VSTR];
      bf16x8 vb0 = *reinterpret_cast<const bf16x8*>(vp + g * 8);
      bf16x8 vb1 = *reinterpret_cast<const bf16x8*>(vp + 32 + g * 8);
      acc[dt] = __builtin_amdgcn_mfma_f32_16x16x32_bf16(pa0, vb0, acc[dt], 0, 0, 0);
      acc[dt] = __builtin_amdgcn_mfma_f32_16x16x32_bf16(pa1, vb1, acc[dt], 0, 0, 0);
    }
  }

  // ---- epilogue: l = acc[5] at fr==0 lane of each group; O = acc / l ----
  #pragma unroll
  for (int j = 0; j < 4; ++j) {
    const float lsum = __shfl(acc[5][j], l & 48);  // lane (g, fr=0)
    const float il = (lsum > 0.f) ? 1.0f / lsum : 0.f;
    const int row = t0 + w * 16 + g * 4 + j;
    #pragma unroll
    for (int dt = 0; dt < 5; ++dt)
      attn_bf[(size_t)row * EMB + h * HD + dt * 16 + fr] = f2bf(acc[dt][j] * il);
  }
}

extern "C" void kernel_launch(void* const* d_in, const int* in_sizes, int n_in,
                              void* d_out, int out_size, void* d_ws, size_t ws_size,
                              hipStream_t stream) {
  const float* hidden = (const float*)d_in[0];
  const int*   cu     = (const int*)d_in[1];
  const float* rope   = (const float*)d_in[2];
  const float* w_qkv  = (const float*)d_in[3];
  const float* w_o    = (const float*)d_in[4];
  const float* qw     = (const float*)d_in[5];
  const float* kw     = (const float*)d_in[6];
  float* out = (float*)d_out;

  const int T = in_sizes[0] / EMB;   // 4096
  const int n_seq = in_sizes[1] - 1; // 8

  // workspace (~34.4MB): qkv_bf | hid_bf(=attn_bf alias) | wqkv_bf | wo_bf | seg
  u16* qkv_bf  = (u16*)d_ws;
  u16* hid_bf  = qkv_bf + (size_t)T * QKV_ROW;
  u16* attn_bf = hid_bf;  // alias: hid_bf dead after qkv GEMM
  u16* wqkv_bf = hid_bf + (size_t)T * EMB;
  u16* wo_bf   = wqkv_bf + (size_t)QKV_ROW * EMB;
  int* segb    = (int*)(wo_bf + (size_t)EMB * EMB);

  const int n_hid = T * EMB, n_wqkv = QKV_ROW * EMB, n_wo = EMB * EMB;
  cvt_bf16<<<(n_hid / 4 + 255) / 256, 256, 0, stream>>>(hidden, hid_bf, n_hid);
  cvt_bf16<<<(n_wqkv / 4 + 255) / 256, 256, 0, stream>>>(w_qkv, wqkv_bf, n_wqkv);
  cvt_bf16<<<(n_wo / 4 + 255) / 256, 256, 0, stream>>>(w_o, wo_bf, n_wo);
  seg_kernel<<<(T + 255) / 256, 256, 0, stream>>>(cu, n_seq, T, segb);

  // qkv = hidden @ w_qkv^T  (bf16 out); grid 480 (%8==0)
  {
    const int gx = QKV_ROW / 128, nwg = gx * (T / 128);
    gemm_bf16<u16><<<nwg, 256, 0, stream>>>(hid_bf, wqkv_bf, qkv_bf, T, QKV_ROW, EMB, gx, nwg);
  }
  norm_rope_bf<<<dim3(T, 5), 256, 0, stream>>>(qkv_bf, rope, qw, kw);
  attn_v4<<<dim3(T / QT, H_Q), 512, 0, stream>>>(qkv_bf, segb, cu, T, attn_bf);
  // out = attn @ w_o^T  (fp32 out); grid 320 (%8==0)
  {
    const int gx = EMB / 128, nwg = gx * (T / 128);
    gemm_bf16<float><<<nwg, 256, 0, stream>>>(attn_bf, wo_bf, out, T, EMB, EMB, gx, nwg);
  }
}